// Round 7
// baseline (466.917 us; speedup 1.0000x reference)
//
#include <hip/hip_runtime.h>
#include <math.h>

// (B,I,H,O,A,M,R) = (16,256,512,256,1024,64,4), IF=471
// ALL inputs fp32, output fp32 (established round 6: bf16 probe invisible in fp32 readback).

__device__ __forceinline__ float sigf(float x){ return 1.0f/(1.0f+expf(-x)); }
__device__ __forceinline__ float softplusf(float x){ return fmaxf(x,0.0f)+log1pf(expf(-fabsf(x))); }

// ---------------- K0: zero bwd accumulator ----------------
__global__ void k_zero(float* __restrict__ p){
  p[blockIdx.x*1024 + threadIdx.x] = 0.0f; // 64x1024
}

// ---------------- K1: LSTM — grid 16, block 512, thread = one j ----------------
__global__ void k_lstm(const float* __restrict__ x, const float* __restrict__ rv,
                       const float* __restrict__ hp, const float* __restrict__ cp,
                       const float* __restrict__ Wx, const float* __restrict__ Wh,
                       const float* __restrict__ bl, float* __restrict__ h_ws){
  __shared__ float inp[1024];
  int b = blockIdx.x, j = threadIdx.x;
  inp[j]     = (j < 256) ? x[b*256+j] : rv[b*256 + (j-256)];
  inp[512+j] = hp[b*512+j];
  __syncthreads();
  float zi = bl[0*512+j], zf = bl[1*512+j], zg = bl[2*512+j], zo = bl[3*512+j];
  for (int k = 0; k < 512; ++k){
    float xv = inp[k], hv = inp[512+k];
    long rx = (long)k*2048;
    zi += xv*Wx[rx + 0*512 + j] + hv*Wh[rx + 0*512 + j];
    zf += xv*Wx[rx + 1*512 + j] + hv*Wh[rx + 1*512 + j];
    zg += xv*Wx[rx + 2*512 + j] + hv*Wh[rx + 2*512 + j];
    zo += xv*Wx[rx + 3*512 + j] + hv*Wh[rx + 3*512 + j];
  }
  float c = sigf(zf)*cp[b*512+j] + sigf(zi)*tanhf(zg);
  h_ws[b*512+j] = sigf(zo)*tanhf(c);
}

// ---------------- K2: iface + out_hidden — grid 16, block 512 ----------------
__global__ void k_iface(const float* __restrict__ h_ws, const float* __restrict__ W_if,
                        const float* __restrict__ b_if, const float* __restrict__ W_hid,
                        const float* __restrict__ b_hid, float* __restrict__ ifr_ws,
                        float* __restrict__ outh_ws){
  __shared__ float hs[512];
  int b = blockIdx.x, t = threadIdx.x;
  hs[t] = h_ws[b*512+t];
  __syncthreads();
  if (t < 471){
    float acc = b_if[t];
    for (int k = 0; k < 512; ++k) acc += hs[k]*W_if[(long)k*471 + t];
    ifr_ws[b*512+t] = acc;
  }
  if (t < 256){
    float acc = b_hid[t];
    for (int k = 0; k < 512; ++k) acc += hs[k]*W_hid[(long)k*256 + t];
    outh_ws[b*256+t] = acc;
  }
}

// ---------------- K3: activations + psi + usage — grid 16, block 1024 ----------------
// layout: k_r[0,256) beta_r[256,260) k_w[260,324) beta_w[324] erase[325,389)
//         write_v[389,453) free[453,457) g_a[457] g_w[458] pi[459,471)
__global__ void k_act_usage(const float* __restrict__ ifr_ws, const float* __restrict__ rw_prev,
                            const float* __restrict__ ww_prev, const float* __restrict__ usage_prev,
                            float* __restrict__ ifa_ws, float* __restrict__ usage_ws){
  int b = blockIdx.x, t = threadIdx.x;
  const float* ifr = ifr_ws + b*512;
  float* ifa = ifa_ws + b*512;
  if (t < 471){
    float v = ifr[t], o = v;
    if ((t >= 256 && t < 260) || t == 324) o = 1.0f + softplusf(v);
    else if ((t >= 325 && t < 389) || (t >= 453 && t < 459)) o = sigf(v);
    ifa[t] = o;
  }
  __syncthreads();
  if (t < 4){
    float p0 = ifr[459+t*3+0], p1 = ifr[459+t*3+1], p2 = ifr[459+t*3+2];
    float mx = fmaxf(p0, fmaxf(p1,p2));
    float e0 = expf(p0-mx), e1 = expf(p1-mx), e2 = expf(p2-mx);
    float s = e0+e1+e2;
    ifa[459+t*3+0]=e0/s; ifa[459+t*3+1]=e1/s; ifa[459+t*3+2]=e2/s;
  }
  __syncthreads();
  float f0 = ifa[453], f1 = ifa[454], f2 = ifa[455], f3 = ifa[456];
  float psi = (1.f - f0*rw_prev[(long)(b*4+0)*1024 + t])
            * (1.f - f1*rw_prev[(long)(b*4+1)*1024 + t])
            * (1.f - f2*rw_prev[(long)(b*4+2)*1024 + t])
            * (1.f - f3*rw_prev[(long)(b*4+3)*1024 + t]);
  float u = usage_prev[b*1024+t], w = ww_prev[b*1024+t];
  usage_ws[b*1024+t] = (u + w - u*w) * psi;
}

// ---------------- K4: rank-based stable argsort + serial cumprod -> alloc ----------------
__global__ void k_alloc(const float* __restrict__ usage_ws, float* __restrict__ alloc_ws){
  int b = blockIdx.x, t = threadIdx.x; // 1024
  __shared__ float u[1024]; __shared__ float srt[1024];
  __shared__ int sidx[1024]; __shared__ float cpp[1024];
  u[t] = usage_ws[b*1024+t];
  __syncthreads();
  float ut = u[t];
  int rank = 0;
  for (int j = 0; j < 1024; ++j){
    float uj = u[j];
    rank += (uj < ut) || (uj == ut && j < t);
  }
  srt[rank] = ut; sidx[rank] = t;
  __syncthreads();
  if (t == 0){
    float p = 1.0f;
    for (int k = 0; k < 1024; ++k){ p *= srt[k]; cpp[k] = p; }
  }
  __syncthreads();
  float cpe = (t == 0) ? 1.0f : cpp[t-1];
  alloc_ws[b*1024 + sidx[t]] = (1.0f - srt[t]) * cpe;
}

// ---------------- K5: write-content softmax + ww — grid 16, block 1024 ----------------
__global__ void k_cw_ww(const float* __restrict__ mem_prev, const float* __restrict__ ifa_ws,
                        const float* __restrict__ alloc_ws, float* __restrict__ ww_ws){
  __shared__ float kw[64]; __shared__ float red[1024]; __shared__ float par[1];
  int b = blockIdx.x, t = threadIdx.x;
  const float* ifa = ifa_ws + b*512;
  if (t < 64) kw[t] = ifa[260 + t];
  __syncthreads();
  if (t == 0){
    float s = 0; for (int m = 0; m < 64; ++m) s += kw[m]*kw[m];
    par[0] = sqrtf(s);
  }
  __syncthreads();
  float kn = par[0], beta = ifa[324], g_a = ifa[457], g_w = ifa[458];
  long base = ((long)b*1024 + t)*64;
  float dot = 0, sq = 0;
  for (int m = 0; m < 64; ++m){
    float v = mem_prev[base+m];
    dot += v*kw[m]; sq += v*v;
  }
  float sc = beta * dot / (kn*sqrtf(sq) + 1e-6f);
  red[t] = sc; __syncthreads();
  for (int s = 512; s > 0; s >>= 1){ if (t < s) red[t] = fmaxf(red[t], red[t+s]); __syncthreads(); }
  float mx = red[0]; __syncthreads();
  float e = expf(sc - mx);
  red[t] = e; __syncthreads();
  for (int s = 512; s > 0; s >>= 1){ if (t < s) red[t] += red[t+s]; __syncthreads(); }
  float cw = e / red[0];
  ww_ws[b*1024+t] = g_w*(g_a*alloc_ws[b*1024+t] + (1.0f-g_a)*cw);
}

// ---------------- K6: mem update + row norms — grid (1024,16), block 64 ----------------
__global__ void k_mem(const float* __restrict__ mem_prev, const float* __restrict__ ww_ws,
                      const float* __restrict__ ifa_ws, float* __restrict__ mem_ws,
                      float* __restrict__ mnorm_ws){
  int a = blockIdx.x, b = blockIdx.y, m = threadIdx.x;
  const float* ifa = ifa_ws + b*512;
  float er = ifa[325+m], wv = ifa[389+m];
  float w = ww_ws[b*1024+a];
  float v = mem_prev[((long)b*1024+a)*64+m]*(1.0f - w*er) + w*wv;
  mem_ws[((long)b*1024+a)*64+m] = v;
  float s = v*v;
  for (int o = 32; o > 0; o >>= 1) s += __shfl_xor(s, o);
  if (m == 0) mnorm_ws[b*1024+a] = sqrtf(s);
}

// ---------------- K7: link -> fwd + bwd via 64x64 LDS tiles ----------------
// link[i,j] = (i==j)?0 : (1-ww_i-ww_j)*L[i,j] + ww_i*prec_j   (never materialized)
// fwd[r,i] = sum_j link[i,j]*rw[r,j];  bwd[r,c] = sum_i link[i,c]*rw[r,i]
// grid (16 bands, 16 b), block 256 = (r = t>>6, lane = t&63)
__global__ __launch_bounds__(256) void k_linkfb(const float* __restrict__ link_prev,
    const float* __restrict__ rw_prev, const float* __restrict__ prec_prev,
    const float* __restrict__ ww_ws, float* __restrict__ fwd_ws, float* __restrict__ bwd_ws){
  __shared__ float Lt[64][65];
  __shared__ float rwI[4][64]; __shared__ float rwJ[4][64];
  __shared__ float wwI[64]; __shared__ float wwJ[64]; __shared__ float pj[64];
  int band = blockIdx.x, b = blockIdx.y, t = threadIdx.x;
  const float* wwb = ww_ws + b*1024;
  int r = t >> 6, il = t & 63;
  rwI[r][il] = rw_prev[(long)(b*4+r)*1024 + band*64 + il];
  if (t < 64) wwI[t] = wwb[band*64 + t];
  float facc = 0.0f;
  const float4* L4 = (const float4*)link_prev;
  for (int ct = 0; ct < 16; ++ct){
    __syncthreads();
    // stage 64x64 tile: 1024 float4s, 4 per thread, lane-consecutive (coalesced 16B/lane)
    for (int q = 0; q < 4; ++q){
      int idx = t + 256*q;             // float4 index in tile
      int row = idx >> 4, c4 = idx & 15;
      float4 v = L4[((long)b << 18) + (long)(band*64 + row)*256 + ct*16 + c4];
      Lt[row][c4*4+0] = v.x; Lt[row][c4*4+1] = v.y;
      Lt[row][c4*4+2] = v.z; Lt[row][c4*4+3] = v.w;
    }
    if (t < 64){ wwJ[t] = wwb[ct*64 + t]; pj[t] = prec_prev[b*1024 + ct*64 + t]; }
    rwJ[r][il] = rw_prev[(long)(b*4+r)*1024 + ct*64 + il];
    __syncthreads();
    // fwd partial: thread (r, il) owns row i = band*64+il
    float wwi = wwI[il];
    float fa = 0.0f;
    for (int jc = 0; jc < 64; ++jc){
      float lv = (1.0f - wwi - wwJ[jc])*Lt[il][jc] + wwi*pj[jc];
      lv = (ct*64 + jc == band*64 + il) ? 0.0f : lv;
      fa += lv * rwJ[r][jc];
    }
    facc += fa;
    // bwd partial: thread (r, cl) owns column c = ct*64+cl over this band's rows
    int cl = il;
    float wwc = wwJ[cl], pc = pj[cl];
    float ba = 0.0f;
    for (int rowl = 0; rowl < 64; ++rowl){
      float lv = (1.0f - wwI[rowl] - wwc)*Lt[rowl][cl] + wwI[rowl]*pc;
      lv = (band*64 + rowl == ct*64 + cl) ? 0.0f : lv;
      ba += lv * rwI[r][rowl];
    }
    atomicAdd(&bwd_ws[(long)(b*4+r)*1024 + ct*64 + cl], ba);
  }
  fwd_ws[(long)(b*4+r)*1024 + band*64 + il] = facc;
}

// ---------------- K8: read content softmax + mix + rv — grid (4,16), block 1024 ----------------
__global__ void k_read(const float* __restrict__ mem_ws, const float* __restrict__ mnorm_ws,
                       const float* __restrict__ ifa_ws, const float* __restrict__ fwd_ws,
                       const float* __restrict__ bwd_ws, float* __restrict__ rv_ws){
  __shared__ float kr[64]; __shared__ float red[1024]; __shared__ float wrs[1024];
  __shared__ float par[1];
  int r = blockIdx.x, b = blockIdx.y, t = threadIdx.x; // a = t
  const float* ifa = ifa_ws + b*512;
  if (t < 64) kr[t] = ifa[r*64 + t];
  __syncthreads();
  if (t == 0){
    float s = 0; for (int m = 0; m < 64; ++m) s += kr[m]*kr[m];
    par[0] = sqrtf(s);
  }
  __syncthreads();
  float kn = par[0], beta = ifa[256 + r];
  long base = ((long)b*1024 + t)*64;
  float dot = 0;
  for (int m = 0; m < 64; ++m) dot += mem_ws[base+m]*kr[m];
  float sc = beta * dot / (kn*mnorm_ws[b*1024+t] + 1e-6f);
  red[t] = sc; __syncthreads();
  for (int s = 512; s > 0; s >>= 1){ if (t < s) red[t] = fmaxf(red[t], red[t+s]); __syncthreads(); }
  float mx = red[0]; __syncthreads();
  float e = expf(sc - mx);
  red[t] = e; __syncthreads();
  for (int s = 512; s > 0; s >>= 1){ if (t < s) red[t] += red[t+s]; __syncthreads(); }
  float cr = e / red[0];
  __syncthreads();
  float p0 = ifa[459+3*r], p1 = ifa[460+3*r], p2 = ifa[461+3*r];
  wrs[t] = p0*bwd_ws[(long)(b*4+r)*1024 + t] + p1*cr + p2*fwd_ws[(long)(b*4+r)*1024 + t];
  __syncthreads();
  // rv[m] = sum_a wrs[a]*mem[a][m]
  int m = t & 63, ch = t >> 6;
  float acc = 0;
  for (int q = 0; q < 64; ++q){
    int a = ch*64 + q;
    acc += wrs[a]*mem_ws[((long)b*1024 + a)*64 + m];
  }
  red[ch*64 + m] = acc;
  __syncthreads();
  if (t < 64){
    float s = 0;
    for (int c2 = 0; c2 < 16; ++c2) s += red[c2*64 + t];
    rv_ws[(b*4+r)*64 + t] = s;
  }
}

// ---------------- K9: out = out_hidden + rv@W_rd + b_rd — grid 16, block 256, fp32 store ----------------
__global__ void k_out(const float* __restrict__ outh_ws, const float* __restrict__ rv_ws,
                      const float* __restrict__ W_rd, const float* __restrict__ b_rd,
                      float* __restrict__ out){
  __shared__ float rvs[256];
  int b = blockIdx.x, o = threadIdx.x;
  rvs[o] = rv_ws[b*256 + o];
  __syncthreads();
  float acc = outh_ws[b*256+o] + b_rd[o];
  for (int q = 0; q < 256; ++q) acc += rvs[q]*W_rd[(long)q*256 + o];
  out[b*256+o] = acc;
}

extern "C" void kernel_launch(void* const* d_in, const int* in_sizes, int n_in,
                              void* d_out, int out_size, void* d_ws, size_t ws_size,
                              hipStream_t stream){
  const float* x          = (const float*)d_in[0];
  const float* h_prev     = (const float*)d_in[1];
  const float* c_prev     = (const float*)d_in[2];
  const float* mem_prev   = (const float*)d_in[3];
  const float* rw_prev    = (const float*)d_in[4];
  const float* ww_prev    = (const float*)d_in[5];
  const float* usage_prev = (const float*)d_in[6];
  const float* prec_prev  = (const float*)d_in[7];
  const float* link_prev  = (const float*)d_in[8];
  const float* rv_prev    = (const float*)d_in[9];
  const float* Wx         = (const float*)d_in[10];
  const float* Wh         = (const float*)d_in[11];
  const float* b_lstm     = (const float*)d_in[12];
  const float* W_hid      = (const float*)d_in[13];
  const float* b_hid      = (const float*)d_in[14];
  const float* W_if       = (const float*)d_in[15];
  const float* b_if       = (const float*)d_in[16];
  const float* W_rd       = (const float*)d_in[17];
  const float* b_rd       = (const float*)d_in[18];
  float* out = (float*)d_out;

  // ws layout (floats), total ~5.11 MB
  float* ws = (float*)d_ws;
  float* h_ws     = ws + 0;          // 8192
  float* ifr_ws   = ws + 8192;       // 8192 (stride 512/b)
  float* ifa_ws   = ws + 16384;      // 8192
  float* outh_ws  = ws + 24576;      // 4096
  float* usage_ws = ws + 28672;      // 16384
  float* alloc_ws = ws + 45056;      // 16384
  float* ww_ws    = ws + 61440;      // 16384
  float* mnorm_ws = ws + 77824;      // 16384
  float* fwd_ws   = ws + 94208;      // 65536
  float* bwd_ws   = ws + 159744;     // 65536
  float* rv_ws    = ws + 225280;     // 4096
  float* mem_ws   = ws + 229376;     // 1048576

  k_zero<<<64,1024,0,stream>>>(bwd_ws);
  k_lstm<<<16,512,0,stream>>>(x, rv_prev, h_prev, c_prev, Wx, Wh, b_lstm, h_ws);
  k_iface<<<16,512,0,stream>>>(h_ws, W_if, b_if, W_hid, b_hid, ifr_ws, outh_ws);
  k_act_usage<<<16,1024,0,stream>>>(ifr_ws, rw_prev, ww_prev, usage_prev, ifa_ws, usage_ws);
  k_alloc<<<16,1024,0,stream>>>(usage_ws, alloc_ws);
  k_cw_ww<<<16,1024,0,stream>>>(mem_prev, ifa_ws, alloc_ws, ww_ws);
  k_mem<<<dim3(1024,16),64,0,stream>>>(mem_prev, ww_ws, ifa_ws, mem_ws, mnorm_ws);
  k_linkfb<<<dim3(16,16),256,0,stream>>>(link_prev, rw_prev, prec_prev, ww_ws, fwd_ws, bwd_ws);
  k_read<<<dim3(4,16),1024,0,stream>>>(mem_ws, mnorm_ws, ifa_ws, fwd_ws, bwd_ws, rv_ws);
  k_out<<<16,256,0,stream>>>(outh_ws, rv_ws, W_rd, b_rd, out);
}

// Round 8
// 340.932 us; speedup vs baseline: 1.3695x; 1.3695x over previous
//
#include <hip/hip_runtime.h>
#include <math.h>

// (B,I,H,O,A,M,R) = (16,256,512,256,1024,64,4), IF=471. All fp32.

__device__ __forceinline__ float sigf(float x){ return 1.0f/(1.0f+expf(-x)); }
__device__ __forceinline__ float softplusf(float x){ return fmaxf(x,0.0f)+log1pf(expf(-fabsf(x))); }

// ---------------- K0: zero bwd accumulator ----------------
__global__ void k_zero(float* __restrict__ p){
  p[blockIdx.x*1024 + threadIdx.x] = 0.0f; // 64x1024
}

// ---------------- K1a: LSTM partial GEMM ----------------
// z[b][n] = cat(x,rv,h) @ cat(Wx;Wh), K=1024, N=2048, B=16.
// grid (ct=8 x kt=16 x bg=2), block 256. Each block: cols ct*256..+256, k kt*64..+64,
// batches bg*8..+8. Writes zpart[kt][b][n].
__global__ __launch_bounds__(256) void k_lstm_part(const float* __restrict__ x,
    const float* __restrict__ rv, const float* __restrict__ hp,
    const float* __restrict__ Wx, const float* __restrict__ Wh,
    float* __restrict__ zpart){
  __shared__ float inp[8][64];
  int ct = blockIdx.x, kt = blockIdx.y, bg = blockIdx.z, t = threadIdx.x;
  for (int i = t; i < 512; i += 256){
    int bb = i >> 6, kk = i & 63;
    int k = kt*64 + kk, b = bg*8 + bb;
    float v = (k < 256) ? x[b*256+k] : (k < 512) ? rv[b*256 + k-256] : hp[b*512 + k-512];
    inp[bb][kk] = v;
  }
  __syncthreads();
  int col = ct*256 + t;
  float acc[8];
  #pragma unroll
  for (int bb = 0; bb < 8; ++bb) acc[bb] = 0.0f;
  for (int kk = 0; kk < 64; ++kk){
    int k = kt*64 + kk;
    float w = (k < 512) ? Wx[(long)k*2048 + col] : Wh[(long)(k-512)*2048 + col];
    #pragma unroll
    for (int bb = 0; bb < 8; ++bb) acc[bb] += inp[bb][kk]*w;
  }
  #pragma unroll
  for (int bb = 0; bb < 8; ++bb)
    zpart[((long)kt*16 + bg*8 + bb)*2048 + col] = acc[bb];
}

// ---------------- K1b: LSTM finish — grid 16, block 512 ----------------
__global__ void k_lstm_fin(const float* __restrict__ zpart, const float* __restrict__ bl,
                           const float* __restrict__ cp, float* __restrict__ h_ws){
  int b = blockIdx.x, j = threadIdx.x;
  float zi = bl[j], zf = bl[512+j], zg = bl[1024+j], zo = bl[1536+j];
  for (int kt = 0; kt < 16; ++kt){
    const float* zp = zpart + ((long)kt*16 + b)*2048;
    zi += zp[j]; zf += zp[512+j]; zg += zp[1024+j]; zo += zp[1536+j];
  }
  float c = sigf(zf)*cp[b*512+j] + sigf(zi)*tanhf(zg);
  h_ws[b*512+j] = sigf(zo)*tanhf(c);
}

// ---------------- K2a: iface/out_hidden partial GEMM ----------------
// cols 0..726: [0,471) -> W_if, [471,727) -> W_hid. K=512 (h).
// grid (ct=3 x kt=16 x bg=2), block 256.
__global__ __launch_bounds__(256) void k_iface_part(const float* __restrict__ h_ws,
    const float* __restrict__ W_if, const float* __restrict__ W_hid,
    float* __restrict__ ifpart){
  __shared__ float hh[8][32];
  int ct = blockIdx.x, kt = blockIdx.y, bg = blockIdx.z, t = threadIdx.x;
  if (t < 256){
    int bb = t >> 5, kk = t & 31;
    hh[bb][kk] = h_ws[(bg*8 + bb)*512 + kt*32 + kk];
  }
  __syncthreads();
  int col = ct*256 + t;
  float acc[8];
  #pragma unroll
  for (int bb = 0; bb < 8; ++bb) acc[bb] = 0.0f;
  if (col < 727){
    for (int kk = 0; kk < 32; ++kk){
      int k = kt*32 + kk;
      float w = (col < 471) ? W_if[(long)k*471 + col] : W_hid[(long)k*256 + (col-471)];
      #pragma unroll
      for (int bb = 0; bb < 8; ++bb) acc[bb] += hh[bb][kk]*w;
    }
    #pragma unroll
    for (int bb = 0; bb < 8; ++bb)
      ifpart[((long)kt*16 + bg*8 + bb)*768 + col] = acc[bb];
  }
}

// ---------------- K2b: iface finish — grid 16, block 768 ----------------
__global__ void k_iface_fin(const float* __restrict__ ifpart, const float* __restrict__ b_if,
                            const float* __restrict__ b_hid, float* __restrict__ ifr_ws,
                            float* __restrict__ outh_ws){
  int b = blockIdx.x, t = threadIdx.x;
  if (t >= 727) return;
  float s = (t < 471) ? b_if[t] : b_hid[t-471];
  for (int kt = 0; kt < 16; ++kt) s += ifpart[((long)kt*16 + b)*768 + t];
  if (t < 471) ifr_ws[b*512 + t] = s;
  else         outh_ws[b*256 + (t-471)] = s;
}

// ---------------- K3: activations + psi + usage — grid 16, block 1024 ----------------
// layout: k_r[0,256) beta_r[256,260) k_w[260,324) beta_w[324] erase[325,389)
//         write_v[389,453) free[453,457) g_a[457] g_w[458] pi[459,471)
__global__ void k_act_usage(const float* __restrict__ ifr_ws, const float* __restrict__ rw_prev,
                            const float* __restrict__ ww_prev, const float* __restrict__ usage_prev,
                            float* __restrict__ ifa_ws, float* __restrict__ usage_ws){
  int b = blockIdx.x, t = threadIdx.x;
  const float* ifr = ifr_ws + b*512;
  float* ifa = ifa_ws + b*512;
  if (t < 471){
    float v = ifr[t], o = v;
    if ((t >= 256 && t < 260) || t == 324) o = 1.0f + softplusf(v);
    else if ((t >= 325 && t < 389) || (t >= 453 && t < 459)) o = sigf(v);
    ifa[t] = o;
  }
  __syncthreads();
  if (t < 4){
    float p0 = ifr[459+t*3+0], p1 = ifr[459+t*3+1], p2 = ifr[459+t*3+2];
    float mx = fmaxf(p0, fmaxf(p1,p2));
    float e0 = expf(p0-mx), e1 = expf(p1-mx), e2 = expf(p2-mx);
    float s = e0+e1+e2;
    ifa[459+t*3+0]=e0/s; ifa[459+t*3+1]=e1/s; ifa[459+t*3+2]=e2/s;
  }
  __syncthreads();
  float f0 = ifa[453], f1 = ifa[454], f2 = ifa[455], f3 = ifa[456];
  float psi = (1.f - f0*rw_prev[(long)(b*4+0)*1024 + t])
            * (1.f - f1*rw_prev[(long)(b*4+1)*1024 + t])
            * (1.f - f2*rw_prev[(long)(b*4+2)*1024 + t])
            * (1.f - f3*rw_prev[(long)(b*4+3)*1024 + t]);
  float u = usage_prev[b*1024+t], w = ww_prev[b*1024+t];
  usage_ws[b*1024+t] = (u + w - u*w) * psi;
}

// ---------------- K4: rank sort + Hillis-Steele cumprod -> alloc ----------------
__global__ void k_alloc(const float* __restrict__ usage_ws, float* __restrict__ alloc_ws){
  int b = blockIdx.x, t = threadIdx.x; // 1024
  __shared__ float u[1024]; __shared__ float srt[1024];
  __shared__ int sidx[1024]; __shared__ float cpp[1024];
  u[t] = usage_ws[b*1024+t];
  __syncthreads();
  float ut = u[t];
  int rank = 0;
  for (int j = 0; j < 1024; ++j){
    float uj = u[j];
    rank += (uj < ut) || (uj == ut && j < t);
  }
  srt[rank] = ut; sidx[rank] = t;
  cpp[rank] = ut;
  __syncthreads();
  for (int off = 1; off < 1024; off <<= 1){
    float tmp = (t >= off) ? cpp[t-off] : 1.0f;
    __syncthreads();
    cpp[t] *= tmp;
    __syncthreads();
  }
  float cpe = (t == 0) ? 1.0f : cpp[t-1];
  alloc_ws[b*1024 + sidx[t]] = (1.0f - srt[t]) * cpe;
}

// ---------------- K5: write-content softmax + ww — grid 16, block 1024 ----------------
__global__ void k_cw_ww(const float* __restrict__ mem_prev, const float* __restrict__ ifa_ws,
                        const float* __restrict__ alloc_ws, float* __restrict__ ww_ws){
  __shared__ float kw[64]; __shared__ float red[1024]; __shared__ float par[1];
  int b = blockIdx.x, t = threadIdx.x;
  const float* ifa = ifa_ws + b*512;
  if (t < 64) kw[t] = ifa[260 + t];
  __syncthreads();
  if (t == 0){
    float s = 0; for (int m = 0; m < 64; ++m) s += kw[m]*kw[m];
    par[0] = sqrtf(s);
  }
  __syncthreads();
  float kn = par[0], beta = ifa[324], g_a = ifa[457], g_w = ifa[458];
  long base = ((long)b*1024 + t)*64;
  float dot = 0, sq = 0;
  for (int m = 0; m < 64; ++m){
    float v = mem_prev[base+m];
    dot += v*kw[m]; sq += v*v;
  }
  float sc = beta * dot / (kn*sqrtf(sq) + 1e-6f);
  red[t] = sc; __syncthreads();
  for (int s = 512; s > 0; s >>= 1){ if (t < s) red[t] = fmaxf(red[t], red[t+s]); __syncthreads(); }
  float mx = red[0]; __syncthreads();
  float e = expf(sc - mx);
  red[t] = e; __syncthreads();
  for (int s = 512; s > 0; s >>= 1){ if (t < s) red[t] += red[t+s]; __syncthreads(); }
  float cw = e / red[0];
  ww_ws[b*1024+t] = g_w*(g_a*alloc_ws[b*1024+t] + (1.0f-g_a)*cw);
}

// ---------------- K6: mem update + row norms — grid (1024,16), block 64 ----------------
__global__ void k_mem(const float* __restrict__ mem_prev, const float* __restrict__ ww_ws,
                      const float* __restrict__ ifa_ws, float* __restrict__ mem_ws,
                      float* __restrict__ mnorm_ws){
  int a = blockIdx.x, b = blockIdx.y, m = threadIdx.x;
  const float* ifa = ifa_ws + b*512;
  float er = ifa[325+m], wv = ifa[389+m];
  float w = ww_ws[b*1024+a];
  float v = mem_prev[((long)b*1024+a)*64+m]*(1.0f - w*er) + w*wv;
  mem_ws[((long)b*1024+a)*64+m] = v;
  float s = v*v;
  for (int o = 32; o > 0; o >>= 1) s += __shfl_xor(s, o);
  if (m == 0) mnorm_ws[b*1024+a] = sqrtf(s);
}

// ---------------- K7: link -> fwd + bwd via 64x64 LDS tiles ----------------
// link[i,j] = (i==j)?0 : (1-ww_i-ww_j)*L[i,j] + ww_i*prec_j   (never materialized)
__global__ __launch_bounds__(256) void k_linkfb(const float* __restrict__ link_prev,
    const float* __restrict__ rw_prev, const float* __restrict__ prec_prev,
    const float* __restrict__ ww_ws, float* __restrict__ fwd_ws, float* __restrict__ bwd_ws){
  __shared__ float Lt[64][65];
  __shared__ float rwI[4][64]; __shared__ float rwJ[4][64];
  __shared__ float wwI[64]; __shared__ float wwJ[64]; __shared__ float pj[64];
  int band = blockIdx.x, b = blockIdx.y, t = threadIdx.x;
  const float* wwb = ww_ws + b*1024;
  int r = t >> 6, il = t & 63;
  rwI[r][il] = rw_prev[(long)(b*4+r)*1024 + band*64 + il];
  if (t < 64) wwI[t] = wwb[band*64 + t];
  float facc = 0.0f;
  const float4* L4 = (const float4*)link_prev;
  for (int ct = 0; ct < 16; ++ct){
    __syncthreads();
    for (int q = 0; q < 4; ++q){
      int idx = t + 256*q;
      int row = idx >> 4, c4 = idx & 15;
      float4 v = L4[((long)b << 18) + (long)(band*64 + row)*256 + ct*16 + c4];
      Lt[row][c4*4+0] = v.x; Lt[row][c4*4+1] = v.y;
      Lt[row][c4*4+2] = v.z; Lt[row][c4*4+3] = v.w;
    }
    if (t < 64){ wwJ[t] = wwb[ct*64 + t]; pj[t] = prec_prev[b*1024 + ct*64 + t]; }
    rwJ[r][il] = rw_prev[(long)(b*4+r)*1024 + ct*64 + il];
    __syncthreads();
    float wwi = wwI[il];
    float fa = 0.0f;
    for (int jc = 0; jc < 64; ++jc){
      float lv = (1.0f - wwi - wwJ[jc])*Lt[il][jc] + wwi*pj[jc];
      lv = (ct*64 + jc == band*64 + il) ? 0.0f : lv;
      fa += lv * rwJ[r][jc];
    }
    facc += fa;
    int cl = il;
    float wwc = wwJ[cl], pc = pj[cl];
    float ba = 0.0f;
    for (int rowl = 0; rowl < 64; ++rowl){
      float lv = (1.0f - wwI[rowl] - wwc)*Lt[rowl][cl] + wwI[rowl]*pc;
      lv = (band*64 + rowl == ct*64 + cl) ? 0.0f : lv;
      ba += lv * rwI[r][rowl];
    }
    atomicAdd(&bwd_ws[(long)(b*4+r)*1024 + ct*64 + cl], ba);
  }
  fwd_ws[(long)(b*4+r)*1024 + band*64 + il] = facc;
}

// ---------------- K8: read content softmax + mix + rv — grid (4,16), block 1024 ----------------
__global__ void k_read(const float* __restrict__ mem_ws, const float* __restrict__ mnorm_ws,
                       const float* __restrict__ ifa_ws, const float* __restrict__ fwd_ws,
                       const float* __restrict__ bwd_ws, float* __restrict__ rv_ws){
  __shared__ float kr[64]; __shared__ float red[1024]; __shared__ float wrs[1024];
  __shared__ float par[1];
  int r = blockIdx.x, b = blockIdx.y, t = threadIdx.x; // a = t
  const float* ifa = ifa_ws + b*512;
  if (t < 64) kr[t] = ifa[r*64 + t];
  __syncthreads();
  if (t == 0){
    float s = 0; for (int m = 0; m < 64; ++m) s += kr[m]*kr[m];
    par[0] = sqrtf(s);
  }
  __syncthreads();
  float kn = par[0], beta = ifa[256 + r];
  long base = ((long)b*1024 + t)*64;
  float dot = 0;
  for (int m = 0; m < 64; ++m) dot += mem_ws[base+m]*kr[m];
  float sc = beta * dot / (kn*mnorm_ws[b*1024+t] + 1e-6f);
  red[t] = sc; __syncthreads();
  for (int s = 512; s > 0; s >>= 1){ if (t < s) red[t] = fmaxf(red[t], red[t+s]); __syncthreads(); }
  float mx = red[0]; __syncthreads();
  float e = expf(sc - mx);
  red[t] = e; __syncthreads();
  for (int s = 512; s > 0; s >>= 1){ if (t < s) red[t] += red[t+s]; __syncthreads(); }
  float cr = e / red[0];
  __syncthreads();
  float p0 = ifa[459+3*r], p1 = ifa[460+3*r], p2 = ifa[461+3*r];
  wrs[t] = p0*bwd_ws[(long)(b*4+r)*1024 + t] + p1*cr + p2*fwd_ws[(long)(b*4+r)*1024 + t];
  __syncthreads();
  int m = t & 63, ch = t >> 6;
  float acc = 0;
  for (int q = 0; q < 64; ++q){
    int a = ch*64 + q;
    acc += wrs[a]*mem_ws[((long)b*1024 + a)*64 + m];
  }
  red[ch*64 + m] = acc;
  __syncthreads();
  if (t < 64){
    float s = 0;
    for (int c2 = 0; c2 < 16; ++c2) s += red[c2*64 + t];
    rv_ws[(b*4+r)*64 + t] = s;
  }
}

// ---------------- K9: out = out_hidden + rv@W_rd + b_rd — grid 16, block 256 ----------------
__global__ void k_out(const float* __restrict__ outh_ws, const float* __restrict__ rv_ws,
                      const float* __restrict__ W_rd, const float* __restrict__ b_rd,
                      float* __restrict__ out){
  __shared__ float rvs[256];
  int b = blockIdx.x, o = threadIdx.x;
  rvs[o] = rv_ws[b*256 + o];
  __syncthreads();
  float acc = outh_ws[b*256+o] + b_rd[o];
  for (int q = 0; q < 256; ++q) acc += rvs[q]*W_rd[(long)q*256 + o];
  out[b*256+o] = acc;
}

extern "C" void kernel_launch(void* const* d_in, const int* in_sizes, int n_in,
                              void* d_out, int out_size, void* d_ws, size_t ws_size,
                              hipStream_t stream){
  const float* x          = (const float*)d_in[0];
  const float* h_prev     = (const float*)d_in[1];
  const float* c_prev     = (const float*)d_in[2];
  const float* mem_prev   = (const float*)d_in[3];
  const float* rw_prev    = (const float*)d_in[4];
  const float* ww_prev    = (const float*)d_in[5];
  const float* usage_prev = (const float*)d_in[6];
  const float* prec_prev  = (const float*)d_in[7];
  const float* link_prev  = (const float*)d_in[8];
  const float* rv_prev    = (const float*)d_in[9];
  const float* Wx         = (const float*)d_in[10];
  const float* Wh         = (const float*)d_in[11];
  const float* b_lstm     = (const float*)d_in[12];
  const float* W_hid      = (const float*)d_in[13];
  const float* b_hid      = (const float*)d_in[14];
  const float* W_if       = (const float*)d_in[15];
  const float* b_if       = (const float*)d_in[16];
  const float* W_rd       = (const float*)d_in[17];
  const float* b_rd       = (const float*)d_in[18];
  float* out = (float*)d_out;

  // ws layout (floats), total ~5.11 MB. zpart/ifpart overlay mem_ws (consumed before k_mem).
  float* ws = (float*)d_ws;
  float* h_ws     = ws + 0;          // 8192
  float* ifr_ws   = ws + 8192;       // 8192 (stride 512/b)
  float* ifa_ws   = ws + 16384;      // 8192
  float* outh_ws  = ws + 24576;      // 4096
  float* usage_ws = ws + 28672;      // 16384
  float* alloc_ws = ws + 45056;      // 16384
  float* ww_ws    = ws + 61440;      // 16384
  float* mnorm_ws = ws + 77824;      // 16384
  float* fwd_ws   = ws + 94208;      // 65536
  float* bwd_ws   = ws + 159744;     // 65536
  float* rv_ws    = ws + 225280;     // 4096
  float* mem_ws   = ws + 229376;     // 1048576
  float* zpart    = mem_ws;          // 524288 (16kt x 16b x 2048) — dead before k_mem
  float* ifpart   = mem_ws + 524288; // 196608 (16kt x 16b x 768)  — dead before k_mem

  k_zero<<<64,1024,0,stream>>>(bwd_ws);
  k_lstm_part<<<dim3(8,16,2),256,0,stream>>>(x, rv_prev, h_prev, Wx, Wh, zpart);
  k_lstm_fin<<<16,512,0,stream>>>(zpart, b_lstm, c_prev, h_ws);
  k_iface_part<<<dim3(3,16,2),256,0,stream>>>(h_ws, W_if, W_hid, ifpart);
  k_iface_fin<<<16,768,0,stream>>>(ifpart, b_if, b_hid, ifr_ws, outh_ws);
  k_act_usage<<<16,1024,0,stream>>>(ifr_ws, rw_prev, ww_prev, usage_prev, ifa_ws, usage_ws);
  k_alloc<<<16,1024,0,stream>>>(usage_ws, alloc_ws);
  k_cw_ww<<<16,1024,0,stream>>>(mem_prev, ifa_ws, alloc_ws, ww_ws);
  k_mem<<<dim3(1024,16),64,0,stream>>>(mem_prev, ww_ws, ifa_ws, mem_ws, mnorm_ws);
  k_linkfb<<<dim3(16,16),256,0,stream>>>(link_prev, rw_prev, prec_prev, ww_ws, fwd_ws, bwd_ws);
  k_read<<<dim3(4,16),1024,0,stream>>>(mem_ws, mnorm_ws, ifa_ws, fwd_ws, bwd_ws, rv_ws);
  k_out<<<16,256,0,stream>>>(outh_ws, rv_ws, W_rd, b_rd, out);
}

// Round 9
// 291.115 us; speedup vs baseline: 1.6039x; 1.1711x over previous
//
#include <hip/hip_runtime.h>
#include <math.h>

// (B,I,H,O,A,M,R) = (16,256,512,256,1024,64,4), IF=471. All fp32.

__device__ __forceinline__ float sigf(float x){ return 1.0f/(1.0f+expf(-x)); }
__device__ __forceinline__ float softplusf(float x){ return fmaxf(x,0.0f)+log1pf(expf(-fabsf(x))); }

// ---------------- K1a: LSTM partial GEMM ----------------
// grid (ct=8 x kt=16 x bg=2), block 256
__global__ __launch_bounds__(256) void k_lstm_part(const float* __restrict__ x,
    const float* __restrict__ rv, const float* __restrict__ hp,
    const float* __restrict__ Wx, const float* __restrict__ Wh,
    float* __restrict__ zpart){
  __shared__ float inp[8][64];
  int ct = blockIdx.x, kt = blockIdx.y, bg = blockIdx.z, t = threadIdx.x;
  for (int i = t; i < 512; i += 256){
    int bb = i >> 6, kk = i & 63;
    int k = kt*64 + kk, b = bg*8 + bb;
    float v = (k < 256) ? x[b*256+k] : (k < 512) ? rv[b*256 + k-256] : hp[b*512 + k-512];
    inp[bb][kk] = v;
  }
  __syncthreads();
  int col = ct*256 + t;
  float acc[8];
  #pragma unroll
  for (int bb = 0; bb < 8; ++bb) acc[bb] = 0.0f;
  for (int kk = 0; kk < 64; ++kk){
    int k = kt*64 + kk;
    float w = (k < 512) ? Wx[(long)k*2048 + col] : Wh[(long)(k-512)*2048 + col];
    #pragma unroll
    for (int bb = 0; bb < 8; ++bb) acc[bb] += inp[bb][kk]*w;
  }
  #pragma unroll
  for (int bb = 0; bb < 8; ++bb)
    zpart[((long)kt*16 + bg*8 + bb)*2048 + col] = acc[bb];
}

// ---------------- K1b: LSTM finish — grid 16, block 512 ----------------
__global__ void k_lstm_fin(const float* __restrict__ zpart, const float* __restrict__ bl,
                           const float* __restrict__ cp, float* __restrict__ h_ws){
  int b = blockIdx.x, j = threadIdx.x;
  float zi = bl[j], zf = bl[512+j], zg = bl[1024+j], zo = bl[1536+j];
  for (int kt = 0; kt < 16; ++kt){
    const float* zp = zpart + ((long)kt*16 + b)*2048;
    zi += zp[j]; zf += zp[512+j]; zg += zp[1024+j]; zo += zp[1536+j];
  }
  float c = sigf(zf)*cp[b*512+j] + sigf(zi)*tanhf(zg);
  h_ws[b*512+j] = sigf(zo)*tanhf(c);
}

// ---------------- K2a: iface/out_hidden partial GEMM — grid (3,16,2), block 256 ----------------
__global__ __launch_bounds__(256) void k_iface_part(const float* __restrict__ h_ws,
    const float* __restrict__ W_if, const float* __restrict__ W_hid,
    float* __restrict__ ifpart){
  __shared__ float hh[8][32];
  int ct = blockIdx.x, kt = blockIdx.y, bg = blockIdx.z, t = threadIdx.x;
  {
    int bb = t >> 5, kk = t & 31;
    hh[bb][kk] = h_ws[(bg*8 + bb)*512 + kt*32 + kk];
  }
  __syncthreads();
  int col = ct*256 + t;
  float acc[8];
  #pragma unroll
  for (int bb = 0; bb < 8; ++bb) acc[bb] = 0.0f;
  if (col < 727){
    for (int kk = 0; kk < 32; ++kk){
      int k = kt*32 + kk;
      float w = (col < 471) ? W_if[(long)k*471 + col] : W_hid[(long)k*256 + (col-471)];
      #pragma unroll
      for (int bb = 0; bb < 8; ++bb) acc[bb] += hh[bb][kk]*w;
    }
    #pragma unroll
    for (int bb = 0; bb < 8; ++bb)
      ifpart[((long)kt*16 + bg*8 + bb)*768 + col] = acc[bb];
  }
}

// ---------------- K2b: iface finish — grid 16, block 768 ----------------
__global__ void k_iface_fin(const float* __restrict__ ifpart, const float* __restrict__ b_if,
                            const float* __restrict__ b_hid, float* __restrict__ ifr_ws,
                            float* __restrict__ outh_ws){
  int b = blockIdx.x, t = threadIdx.x;
  if (t >= 727) return;
  float s = (t < 471) ? b_if[t] : b_hid[t-471];
  for (int kt = 0; kt < 16; ++kt) s += ifpart[((long)kt*16 + b)*768 + t];
  if (t < 471) ifr_ws[b*512 + t] = s;
  else         outh_ws[b*256 + (t-471)] = s;
}

// ---------------- K3: activations + psi + usage — grid 16, block 1024 ----------------
// layout: k_r[0,256) beta_r[256,260) k_w[260,324) beta_w[324] erase[325,389)
//         write_v[389,453) free[453,457) g_a[457] g_w[458] pi[459,471)
__global__ void k_act_usage(const float* __restrict__ ifr_ws, const float* __restrict__ rw_prev,
                            const float* __restrict__ ww_prev, const float* __restrict__ usage_prev,
                            float* __restrict__ ifa_ws, float* __restrict__ usage_ws){
  int b = blockIdx.x, t = threadIdx.x;
  const float* ifr = ifr_ws + b*512;
  float* ifa = ifa_ws + b*512;
  if (t < 471){
    float v = ifr[t], o = v;
    if ((t >= 256 && t < 260) || t == 324) o = 1.0f + softplusf(v);
    else if ((t >= 325 && t < 389) || (t >= 453 && t < 459)) o = sigf(v);
    ifa[t] = o;
  }
  __syncthreads();
  if (t < 4){
    float p0 = ifr[459+t*3+0], p1 = ifr[459+t*3+1], p2 = ifr[459+t*3+2];
    float mx = fmaxf(p0, fmaxf(p1,p2));
    float e0 = expf(p0-mx), e1 = expf(p1-mx), e2 = expf(p2-mx);
    float s = e0+e1+e2;
    ifa[459+t*3+0]=e0/s; ifa[459+t*3+1]=e1/s; ifa[459+t*3+2]=e2/s;
  }
  __syncthreads();
  float f0 = ifa[453], f1 = ifa[454], f2 = ifa[455], f3 = ifa[456];
  float psi = (1.f - f0*rw_prev[(long)(b*4+0)*1024 + t])
            * (1.f - f1*rw_prev[(long)(b*4+1)*1024 + t])
            * (1.f - f2*rw_prev[(long)(b*4+2)*1024 + t])
            * (1.f - f3*rw_prev[(long)(b*4+3)*1024 + t]);
  float u = usage_prev[b*1024+t], w = ww_prev[b*1024+t];
  usage_ws[b*1024+t] = (u + w - u*w) * psi;
}

// ---------------- K4: rank sort + Hillis-Steele cumprod -> alloc — grid 16, block 1024 ----------------
__global__ void k_alloc(const float* __restrict__ usage_ws, float* __restrict__ alloc_ws){
  int b = blockIdx.x, t = threadIdx.x;
  __shared__ float u[1024]; __shared__ float srt[1024];
  __shared__ int sidx[1024]; __shared__ float cpp[1024];
  u[t] = usage_ws[b*1024+t];
  __syncthreads();
  float ut = u[t];
  int rank = 0;
  for (int j = 0; j < 1024; ++j){
    float uj = u[j];
    rank += (uj < ut) || (uj == ut && j < t);
  }
  srt[rank] = ut; sidx[rank] = t;
  cpp[rank] = ut;
  __syncthreads();
  for (int off = 1; off < 1024; off <<= 1){
    float tmp = (t >= off) ? cpp[t-off] : 1.0f;
    __syncthreads();
    cpp[t] *= tmp;
    __syncthreads();
  }
  float cpe = (t == 0) ? 1.0f : cpp[t-1];
  alloc_ws[b*1024 + sidx[t]] = (1.0f - srt[t]) * cpe;
}

// ---------------- K5a: write-content scores (coalesced, wave per row) ----------------
// grid (16 atile, 16 b), block 256 = 4 waves x 16 rows each
__global__ __launch_bounds__(256) void k_wscore(const float* __restrict__ mem_prev,
    const float* __restrict__ ifa_ws, float* __restrict__ wsc_ws){
  int at = blockIdx.x, b = blockIdx.y;
  int t = threadIdx.x, w = t >> 6, m = t & 63;
  const float* ifa = ifa_ws + b*512;
  float kwm = ifa[260+m], beta = ifa[324];
  float knsq = kwm*kwm;
  for (int o = 32; o > 0; o >>= 1) knsq += __shfl_xor(knsq, o);
  float kn = sqrtf(knsq);
  for (int rr = 0; rr < 16; ++rr){
    int a = at*64 + w*16 + rr;
    float v = mem_prev[((long)b*1024+a)*64+m];
    float d = v*kwm, sq = v*v;
    for (int o = 32; o > 0; o >>= 1){ d += __shfl_xor(d,o); sq += __shfl_xor(sq,o); }
    if (m == 0) wsc_ws[b*1024+a] = beta*d/(kn*sqrtf(sq)+1e-6f);
  }
}

// ---------------- K5b: softmax(wsc) + ww — grid 16, block 1024 ----------------
__global__ void k_cw_ww(const float* __restrict__ wsc_ws, const float* __restrict__ ifa_ws,
                        const float* __restrict__ alloc_ws, float* __restrict__ ww_ws){
  __shared__ float red[1024];
  int b = blockIdx.x, t = threadIdx.x;
  const float* ifa = ifa_ws + b*512;
  float g_a = ifa[457], g_w = ifa[458];
  float sc = wsc_ws[b*1024+t];
  red[t] = sc; __syncthreads();
  for (int s = 512; s > 0; s >>= 1){ if (t < s) red[t] = fmaxf(red[t], red[t+s]); __syncthreads(); }
  float mx = red[0]; __syncthreads();
  float e = expf(sc - mx);
  red[t] = e; __syncthreads();
  for (int s = 512; s > 0; s >>= 1){ if (t < s) red[t] += red[t+s]; __syncthreads(); }
  float cw = e / red[0];
  ww_ws[b*1024+t] = g_w*(g_a*alloc_ws[b*1024+t] + (1.0f-g_a)*cw);
}

// ---------------- K6: mem update + norms + 4 read-key dots (coalesced) ----------------
// grid (16 atile, 16 b), block 256 = 4 waves x 16 rows
__global__ __launch_bounds__(256) void k_memr(const float* __restrict__ mem_prev,
    const float* __restrict__ ww_ws, const float* __restrict__ ifa_ws,
    float* __restrict__ mem_ws, float* __restrict__ mnorm_ws, float* __restrict__ rdot_ws){
  int at = blockIdx.x, b = blockIdx.y;
  int t = threadIdx.x, w = t >> 6, m = t & 63;
  const float* ifa = ifa_ws + b*512;
  float er = ifa[325+m], wv = ifa[389+m];
  float k0 = ifa[m], k1 = ifa[64+m], k2 = ifa[128+m], k3 = ifa[192+m];
  for (int rr = 0; rr < 16; ++rr){
    int a = at*64 + w*16 + rr;
    float ww = ww_ws[b*1024+a];
    float v = mem_prev[((long)b*1024+a)*64+m]*(1.0f - ww*er) + ww*wv;
    mem_ws[((long)b*1024+a)*64+m] = v;
    float sq = v*v, d0 = v*k0, d1 = v*k1, d2 = v*k2, d3 = v*k3;
    for (int o = 32; o > 0; o >>= 1){
      sq += __shfl_xor(sq,o); d0 += __shfl_xor(d0,o); d1 += __shfl_xor(d1,o);
      d2 += __shfl_xor(d2,o); d3 += __shfl_xor(d3,o);
    }
    if (m == 0){
      mnorm_ws[b*1024+a] = sqrtf(sq);
      rdot_ws[(long)(b*4+0)*1024+a] = d0; rdot_ws[(long)(b*4+1)*1024+a] = d1;
      rdot_ws[(long)(b*4+2)*1024+a] = d2; rdot_ws[(long)(b*4+3)*1024+a] = d3;
    }
  }
}

// ---------------- K7a: link -> fwd/bwd partials, no atomics ----------------
// grid (band 16, ctg 4, b 16) = 1024 blocks, block 256. Each block: 4 tiles of 64x64.
// link[i,j] = (i==j)?0 : (1-ww_i-ww_j)*L[i,j] + ww_i*prec_j
__global__ __launch_bounds__(256) void k_linkfb(const float* __restrict__ link_prev,
    const float* __restrict__ rw_prev, const float* __restrict__ prec_prev,
    const float* __restrict__ ww_ws, float* __restrict__ fwd_part, float* __restrict__ bwd_part){
  __shared__ float Lt[64][65];
  __shared__ float rwI[4][64]; __shared__ float rwJ[4][64];
  __shared__ float wwI[64]; __shared__ float wwJ[64]; __shared__ float pj[64];
  int band = blockIdx.x, ctg = blockIdx.y, b = blockIdx.z, t = threadIdx.x;
  const float* wwb = ww_ws + b*1024;
  int r = t >> 6, il = t & 63;
  rwI[r][il] = rw_prev[(long)(b*4+r)*1024 + band*64 + il];
  if (t < 64) wwI[t] = wwb[band*64 + t];
  float facc = 0.0f;
  const float4* L4 = (const float4*)link_prev;
  for (int q4 = 0; q4 < 4; ++q4){
    int ct = ctg*4 + q4;
    __syncthreads();
    for (int q = 0; q < 4; ++q){
      int idx = t + 256*q;
      int row = idx >> 4, c4 = idx & 15;
      float4 v = L4[((long)b << 18) + (long)(band*64 + row)*256 + ct*16 + c4];
      Lt[row][c4*4+0] = v.x; Lt[row][c4*4+1] = v.y;
      Lt[row][c4*4+2] = v.z; Lt[row][c4*4+3] = v.w;
    }
    if (t < 64){ wwJ[t] = wwb[ct*64 + t]; pj[t] = prec_prev[b*1024 + ct*64 + t]; }
    rwJ[r][il] = rw_prev[(long)(b*4+r)*1024 + ct*64 + il];
    __syncthreads();
    // fwd: thread (r, il) owns row i = band*64+il
    float wwi = wwI[il];
    float fa = 0.0f;
    for (int jc = 0; jc < 64; ++jc){
      float lv = (1.0f - wwi - wwJ[jc])*Lt[il][jc] + wwi*pj[jc];
      lv = (ct*64 + jc == band*64 + il) ? 0.0f : lv;
      fa += lv * rwJ[r][jc];
    }
    facc += fa;
    // bwd: thread (r, cl) owns column c = ct*64+cl over this band's 64 rows
    int cl = il;
    float wwc = wwJ[cl], pc = pj[cl];
    float ba = 0.0f;
    for (int rowl = 0; rowl < 64; ++rowl){
      float lv = (1.0f - wwI[rowl] - wwc)*Lt[rowl][cl] + wwI[rowl]*pc;
      lv = (band*64 + rowl == ct*64 + cl) ? 0.0f : lv;
      ba += lv * rwI[r][rowl];
    }
    bwd_part[(long)band*65536 + (long)b*4096 + r*1024 + ct*64 + cl] = ba;
  }
  fwd_part[(long)ctg*65536 + (long)b*4096 + r*1024 + band*64 + il] = facc;
}

// ---------------- K7b: reduce partials — grid 64, block 1024 ----------------
__global__ void k_fbred(const float* __restrict__ fwd_part, const float* __restrict__ bwd_part,
                        float* __restrict__ fwd_ws, float* __restrict__ bwd_ws){
  int idx = blockIdx.x*1024 + threadIdx.x; // (b*4+r)*1024 + i
  float f = 0.0f;
  #pragma unroll
  for (int c = 0; c < 4; ++c) f += fwd_part[(long)c*65536 + idx];
  fwd_ws[idx] = f;
  float bsum = 0.0f;
  #pragma unroll
  for (int band = 0; band < 16; ++band) bsum += bwd_part[(long)band*65536 + idx];
  bwd_ws[idx] = bsum;
}

// ---------------- K8: read softmax + mix + rv — grid (4,16), block 1024 ----------------
__global__ void k_read(const float* __restrict__ rdot_ws, const float* __restrict__ mnorm_ws,
                       const float* __restrict__ ifa_ws, const float* __restrict__ fwd_ws,
                       const float* __restrict__ bwd_ws, const float* __restrict__ mem_ws,
                       float* __restrict__ rv_ws){
  __shared__ float red[1024]; __shared__ float wrs[1024]; __shared__ float par[1];
  int r = blockIdx.x, b = blockIdx.y, t = threadIdx.x; // a = t
  const float* ifa = ifa_ws + b*512;
  if (t == 0){
    float s = 0;
    for (int m = 0; m < 64; ++m){ float v = ifa[r*64+m]; s += v*v; }
    par[0] = sqrtf(s);
  }
  __syncthreads();
  float kn = par[0], beta = ifa[256 + r];
  float sc = beta * rdot_ws[(long)(b*4+r)*1024 + t] / (kn*mnorm_ws[b*1024+t] + 1e-6f);
  red[t] = sc; __syncthreads();
  for (int s = 512; s > 0; s >>= 1){ if (t < s) red[t] = fmaxf(red[t], red[t+s]); __syncthreads(); }
  float mx = red[0]; __syncthreads();
  float e = expf(sc - mx);
  red[t] = e; __syncthreads();
  for (int s = 512; s > 0; s >>= 1){ if (t < s) red[t] += red[t+s]; __syncthreads(); }
  float cr = e / red[0];
  __syncthreads();
  float p0 = ifa[459+3*r], p1 = ifa[460+3*r], p2 = ifa[461+3*r];
  wrs[t] = p0*bwd_ws[(long)(b*4+r)*1024 + t] + p1*cr + p2*fwd_ws[(long)(b*4+r)*1024 + t];
  __syncthreads();
  int m = t & 63, ch = t >> 6;
  float acc = 0;
  for (int q = 0; q < 64; ++q){
    int a = ch*64 + q;
    acc += wrs[a]*mem_ws[((long)b*1024 + a)*64 + m];
  }
  red[ch*64 + m] = acc;
  __syncthreads();
  if (t < 64){
    float s = 0;
    for (int c2 = 0; c2 < 16; ++c2) s += red[c2*64 + t];
    rv_ws[(b*4+r)*64 + t] = s;
  }
}

// ---------------- K9: out = out_hidden + rv@W_rd + b_rd — grid 16, block 256 ----------------
__global__ void k_out(const float* __restrict__ outh_ws, const float* __restrict__ rv_ws,
                      const float* __restrict__ W_rd, const float* __restrict__ b_rd,
                      float* __restrict__ out){
  __shared__ float rvs[256];
  int b = blockIdx.x, o = threadIdx.x;
  rvs[o] = rv_ws[b*256 + o];
  __syncthreads();
  float acc = outh_ws[b*256+o] + b_rd[o];
  for (int q = 0; q < 256; ++q) acc += rvs[q]*W_rd[(long)q*256 + o];
  out[b*256+o] = acc;
}

extern "C" void kernel_launch(void* const* d_in, const int* in_sizes, int n_in,
                              void* d_out, int out_size, void* d_ws, size_t ws_size,
                              hipStream_t stream){
  const float* x          = (const float*)d_in[0];
  const float* h_prev     = (const float*)d_in[1];
  const float* c_prev     = (const float*)d_in[2];
  const float* mem_prev   = (const float*)d_in[3];
  const float* rw_prev    = (const float*)d_in[4];
  const float* ww_prev    = (const float*)d_in[5];
  const float* usage_prev = (const float*)d_in[6];
  const float* prec_prev  = (const float*)d_in[7];
  const float* link_prev  = (const float*)d_in[8];
  const float* rv_prev    = (const float*)d_in[9];
  const float* Wx         = (const float*)d_in[10];
  const float* Wh         = (const float*)d_in[11];
  const float* b_lstm     = (const float*)d_in[12];
  const float* W_hid      = (const float*)d_in[13];
  const float* b_hid      = (const float*)d_in[14];
  const float* W_if       = (const float*)d_in[15];
  const float* b_if       = (const float*)d_in[16];
  const float* W_rd       = (const float*)d_in[17];
  const float* b_rd       = (const float*)d_in[18];
  float* out = (float*)d_out;

  // ws layout (floats), ~11.5 MB total
  float* ws = (float*)d_ws;
  float* h_ws     = ws + 0;          // 8192
  float* ifr_ws   = ws + 8192;       // 8192
  float* ifa_ws   = ws + 16384;      // 8192
  float* outh_ws  = ws + 24576;      // 4096
  float* usage_ws = ws + 28672;      // 16384
  float* alloc_ws = ws + 45056;      // 16384
  float* ww_ws    = ws + 61440;      // 16384
  float* mnorm_ws = ws + 77824;      // 16384
  float* wsc_ws   = ws + 94208;      // 16384
  float* rv_ws    = ws + 110592;     // 4096
  float* fwd_ws   = ws + 114688;     // 65536
  float* bwd_ws   = ws + 180224;     // 65536
  float* rdot_ws  = ws + 245760;     // 65536
  float* mem_ws   = ws + 311296;     // 1048576
  float* fwd_part = ws + 1359872;    // 262144 (4 ctg x 65536)
  float* bwd_part = ws + 1622016;    // 1048576 (16 band x 65536)
  float* zpart    = mem_ws;          // 524288 overlay (dead before k_memr)
  float* ifpart   = mem_ws + 524288; // 196608 overlay

  k_lstm_part<<<dim3(8,16,2),256,0,stream>>>(x, rv_prev, h_prev, Wx, Wh, zpart);
  k_lstm_fin<<<16,512,0,stream>>>(zpart, b_lstm, c_prev, h_ws);
  k_iface_part<<<dim3(3,16,2),256,0,stream>>>(h_ws, W_if, W_hid, ifpart);
  k_iface_fin<<<16,768,0,stream>>>(ifpart, b_if, b_hid, ifr_ws, outh_ws);
  k_act_usage<<<16,1024,0,stream>>>(ifr_ws, rw_prev, ww_prev, usage_prev, ifa_ws, usage_ws);
  k_alloc<<<16,1024,0,stream>>>(usage_ws, alloc_ws);
  k_wscore<<<dim3(16,16),256,0,stream>>>(mem_prev, ifa_ws, wsc_ws);
  k_cw_ww<<<16,1024,0,stream>>>(wsc_ws, ifa_ws, alloc_ws, ww_ws);
  k_memr<<<dim3(16,16),256,0,stream>>>(mem_prev, ww_ws, ifa_ws, mem_ws, mnorm_ws, rdot_ws);
  k_linkfb<<<dim3(16,4,16),256,0,stream>>>(link_prev, rw_prev, prec_prev, ww_ws, fwd_part, bwd_part);
  k_fbred<<<64,1024,0,stream>>>(fwd_part, bwd_part, fwd_ws, bwd_ws);
  k_read<<<dim3(4,16),1024,0,stream>>>(rdot_ws, mnorm_ws, ifa_ws, fwd_ws, bwd_ws, mem_ws, rv_ws);
  k_out<<<16,256,0,stream>>>(outh_ws, rv_ws, W_rd, b_rd, out);
}

// Round 10
// 270.181 us; speedup vs baseline: 1.7282x; 1.0775x over previous
//
#include <hip/hip_runtime.h>
#include <math.h>

// (B,I,H,O,A,M,R) = (16,256,512,256,1024,64,4), IF=471. All fp32.

__device__ __forceinline__ float sigf(float x){ return 1.0f/(1.0f+expf(-x)); }
__device__ __forceinline__ float softplusf(float x){ return fmaxf(x,0.0f)+log1pf(expf(-fabsf(x))); }

// ---------------- K1a: LSTM partial GEMM — grid (8,16,2), block 256 ----------------
__global__ __launch_bounds__(256) void k_lstm_part(const float* __restrict__ x,
    const float* __restrict__ rv, const float* __restrict__ hp,
    const float* __restrict__ Wx, const float* __restrict__ Wh,
    float* __restrict__ zpart){
  __shared__ float inp[8][64];
  int ct = blockIdx.x, kt = blockIdx.y, bg = blockIdx.z, t = threadIdx.x;
  for (int i = t; i < 512; i += 256){
    int bb = i >> 6, kk = i & 63;
    int k = kt*64 + kk, b = bg*8 + bb;
    float v = (k < 256) ? x[b*256+k] : (k < 512) ? rv[b*256 + k-256] : hp[b*512 + k-512];
    inp[bb][kk] = v;
  }
  __syncthreads();
  int col = ct*256 + t;
  float acc[8];
  #pragma unroll
  for (int bb = 0; bb < 8; ++bb) acc[bb] = 0.0f;
  for (int kk = 0; kk < 64; ++kk){
    int k = kt*64 + kk;
    float w = (k < 512) ? Wx[(long)k*2048 + col] : Wh[(long)(k-512)*2048 + col];
    #pragma unroll
    for (int bb = 0; bb < 8; ++bb) acc[bb] += inp[bb][kk]*w;
  }
  #pragma unroll
  for (int bb = 0; bb < 8; ++bb)
    zpart[((long)kt*16 + bg*8 + bb)*2048 + col] = acc[bb];
}

// ---------------- K1b: LSTM finish — grid (4 jt, 16 b), block 128 ----------------
__global__ void k_lstm_fin(const float* __restrict__ zpart, const float* __restrict__ bl,
                           const float* __restrict__ cp, float* __restrict__ h_ws){
  int jt = blockIdx.x, b = blockIdx.y, j = jt*128 + threadIdx.x;
  float zi = bl[j], zf = bl[512+j], zg = bl[1024+j], zo = bl[1536+j];
  for (int kt = 0; kt < 16; ++kt){
    const float* zp = zpart + ((long)kt*16 + b)*2048;
    zi += zp[j]; zf += zp[512+j]; zg += zp[1024+j]; zo += zp[1536+j];
  }
  float c = sigf(zf)*cp[b*512+j] + sigf(zi)*tanhf(zg);
  h_ws[b*512+j] = sigf(zo)*tanhf(c);
}

// ---------------- K2a: iface/out_hidden partial GEMM — grid (3,16,2), block 256 ----------------
__global__ __launch_bounds__(256) void k_iface_part(const float* __restrict__ h_ws,
    const float* __restrict__ W_if, const float* __restrict__ W_hid,
    float* __restrict__ ifpart){
  __shared__ float hh[8][32];
  int ct = blockIdx.x, kt = blockIdx.y, bg = blockIdx.z, t = threadIdx.x;
  {
    int bb = t >> 5, kk = t & 31;
    hh[bb][kk] = h_ws[(bg*8 + bb)*512 + kt*32 + kk];
  }
  __syncthreads();
  int col = ct*256 + t;
  float acc[8];
  #pragma unroll
  for (int bb = 0; bb < 8; ++bb) acc[bb] = 0.0f;
  if (col < 727){
    for (int kk = 0; kk < 32; ++kk){
      int k = kt*32 + kk;
      float w = (col < 471) ? W_if[(long)k*471 + col] : W_hid[(long)k*256 + (col-471)];
      #pragma unroll
      for (int bb = 0; bb < 8; ++bb) acc[bb] += hh[bb][kk]*w;
    }
    #pragma unroll
    for (int bb = 0; bb < 8; ++bb)
      ifpart[((long)kt*16 + bg*8 + bb)*768 + col] = acc[bb];
  }
}

// ---------------- K2b: iface finish — grid 16, block 768 ----------------
__global__ void k_iface_fin(const float* __restrict__ ifpart, const float* __restrict__ b_if,
                            const float* __restrict__ b_hid, float* __restrict__ ifr_ws,
                            float* __restrict__ outh_ws){
  int b = blockIdx.x, t = threadIdx.x;
  if (t >= 727) return;
  float s = (t < 471) ? b_if[t] : b_hid[t-471];
  for (int kt = 0; kt < 16; ++kt) s += ifpart[((long)kt*16 + b)*768 + t];
  if (t < 471) ifr_ws[b*512 + t] = s;
  else         outh_ws[b*256 + (t-471)] = s;
}

// ---------------- K3: FUSED activations + psi + usage + sort + alloc — grid 16, block 1024 ----------------
// iface layout: k_r[0,256) beta_r[256,260) k_w[260,324) beta_w[324] erase[325,389)
//               write_v[389,453) free[453,457) g_a[457] g_w[458] pi[459,471)
__global__ void k_act_alloc(const float* __restrict__ ifr_ws, const float* __restrict__ rw_prev,
                            const float* __restrict__ ww_prev, const float* __restrict__ usage_prev,
                            float* __restrict__ ifa_ws, float* __restrict__ alloc_ws){
  __shared__ float sifa[480];
  __shared__ float u[1024]; __shared__ float srt[1024];
  __shared__ int sidx[1024]; __shared__ float cpp[1024];
  int b = blockIdx.x, t = threadIdx.x;
  const float* ifr = ifr_ws + b*512;
  if (t < 471){
    float v = ifr[t], o = v;
    if ((t >= 256 && t < 260) || t == 324) o = 1.0f + softplusf(v);
    else if ((t >= 325 && t < 389) || (t >= 453 && t < 459)) o = sigf(v);
    sifa[t] = o;
  }
  __syncthreads();
  if (t < 4){
    float p0 = ifr[459+t*3+0], p1 = ifr[459+t*3+1], p2 = ifr[459+t*3+2];
    float mx = fmaxf(p0, fmaxf(p1,p2));
    float e0 = expf(p0-mx), e1 = expf(p1-mx), e2 = expf(p2-mx);
    float s = e0+e1+e2;
    sifa[459+t*3+0]=e0/s; sifa[459+t*3+1]=e1/s; sifa[459+t*3+2]=e2/s;
  }
  __syncthreads();
  if (t < 471) ifa_ws[b*512 + t] = sifa[t];
  float f0 = sifa[453], f1 = sifa[454], f2 = sifa[455], f3 = sifa[456];
  float psi = (1.f - f0*rw_prev[(long)(b*4+0)*1024 + t])
            * (1.f - f1*rw_prev[(long)(b*4+1)*1024 + t])
            * (1.f - f2*rw_prev[(long)(b*4+2)*1024 + t])
            * (1.f - f3*rw_prev[(long)(b*4+3)*1024 + t]);
  float uu = usage_prev[b*1024+t], w = ww_prev[b*1024+t];
  u[t] = (uu + w - uu*w) * psi;
  __syncthreads();
  float ut = u[t];
  int rank = 0;
  for (int j = 0; j < 1024; ++j){
    float uj = u[j];
    rank += (uj < ut) || (uj == ut && j < t);
  }
  srt[rank] = ut; sidx[rank] = t; cpp[rank] = ut;
  __syncthreads();
  for (int off = 1; off < 1024; off <<= 1){
    float tmp = (t >= off) ? cpp[t-off] : 1.0f;
    __syncthreads();
    cpp[t] *= tmp;
    __syncthreads();
  }
  float cpe = (t == 0) ? 1.0f : cpp[t-1];
  alloc_ws[b*1024 + sidx[t]] = (1.0f - srt[t]) * cpe;
}

// ---------------- K4: write-content scores — grid (16 at,16 b), block 256 ----------------
__global__ __launch_bounds__(256) void k_wscore(const float* __restrict__ mem_prev,
    const float* __restrict__ ifa_ws, float* __restrict__ wsc_ws){
  int at = blockIdx.x, b = blockIdx.y;
  int t = threadIdx.x, w = t >> 6, m = t & 63;
  const float* ifa = ifa_ws + b*512;
  float kwm = ifa[260+m], beta = ifa[324];
  float knsq = kwm*kwm;
  for (int o = 32; o > 0; o >>= 1) knsq += __shfl_xor(knsq, o);
  float kn = sqrtf(knsq);
  for (int rr = 0; rr < 16; ++rr){
    int a = at*64 + w*16 + rr;
    float v = mem_prev[((long)b*1024+a)*64+m];
    float d = v*kwm, sq = v*v;
    for (int o = 32; o > 0; o >>= 1){ d += __shfl_xor(d,o); sq += __shfl_xor(sq,o); }
    if (m == 0) wsc_ws[b*1024+a] = beta*d/(kn*sqrtf(sq)+1e-6f);
  }
}

// ---------------- K5: softmax(wsc) + ww + e=ww*rw — grid 16, block 1024 ----------------
__global__ void k_cw_ww(const float* __restrict__ wsc_ws, const float* __restrict__ ifa_ws,
                        const float* __restrict__ alloc_ws, const float* __restrict__ rw_prev,
                        float* __restrict__ ww_ws, float* __restrict__ e_ws){
  __shared__ float red[1024];
  int b = blockIdx.x, t = threadIdx.x;
  const float* ifa = ifa_ws + b*512;
  float g_a = ifa[457], g_w = ifa[458];
  float sc = wsc_ws[b*1024+t];
  red[t] = sc; __syncthreads();
  for (int s = 512; s > 0; s >>= 1){ if (t < s) red[t] = fmaxf(red[t], red[t+s]); __syncthreads(); }
  float mx = red[0]; __syncthreads();
  float e = expf(sc - mx);
  red[t] = e; __syncthreads();
  for (int s = 512; s > 0; s >>= 1){ if (t < s) red[t] += red[t+s]; __syncthreads(); }
  float cw = e / red[0];
  float ww = g_w*(g_a*alloc_ws[b*1024+t] + (1.0f-g_a)*cw);
  ww_ws[b*1024+t] = ww;
  #pragma unroll
  for (int r = 0; r < 4; ++r)
    e_ws[(long)(b*4+r)*1024 + t] = ww * rw_prev[(long)(b*4+r)*1024 + t];
}

// ---------------- K6: updated-mem norms + 4 read-key dots (mem recomputed, not stored) ----------------
// grid (16 at, 16 b), block 256 = 4 waves x 16 rows
__global__ __launch_bounds__(256) void k_score(const float* __restrict__ mem_prev,
    const float* __restrict__ ww_ws, const float* __restrict__ ifa_ws,
    float* __restrict__ mnorm_ws, float* __restrict__ rdot_ws){
  int at = blockIdx.x, b = blockIdx.y;
  int t = threadIdx.x, w = t >> 6, m = t & 63;
  const float* ifa = ifa_ws + b*512;
  float er = ifa[325+m], wv = ifa[389+m];
  float k0 = ifa[m], k1 = ifa[64+m], k2 = ifa[128+m], k3 = ifa[192+m];
  for (int rr = 0; rr < 16; ++rr){
    int a = at*64 + w*16 + rr;
    float ww = ww_ws[b*1024+a];
    float v = mem_prev[((long)b*1024+a)*64+m]*(1.0f - ww*er) + ww*wv;
    float sq = v*v, d0 = v*k0, d1 = v*k1, d2 = v*k2, d3 = v*k3;
    for (int o = 32; o > 0; o >>= 1){
      sq += __shfl_xor(sq,o); d0 += __shfl_xor(d0,o); d1 += __shfl_xor(d1,o);
      d2 += __shfl_xor(d2,o); d3 += __shfl_xor(d3,o);
    }
    if (m == 0){
      mnorm_ws[b*1024+a] = sqrtf(sq);
      rdot_ws[(long)(b*4+0)*1024+a] = d0; rdot_ws[(long)(b*4+1)*1024+a] = d1;
      rdot_ws[(long)(b*4+2)*1024+a] = d2; rdot_ws[(long)(b*4+3)*1024+a] = d3;
    }
  }
}

// ---------------- K7a: link fwd/bwd via affine decomposition ----------------
// link = (1-ww_i-ww_j)L + ww_i p_j  (diag zeroed via correction)
// fwd[r,i] = (1-ww_i) SUM_j L a[r,j] - SUM_j L e[r,j] + ww_i SUM_j p_j a[r,j]   (a=rw, e=ww*rw)
// bwd[r,c] = (1-ww_c) SUM_i L a[r,i] - SUM_i L e[r,i] + p_c SUM_i e[r,i]
// grid (band 16, ct 16, b 16) = 4096 blocks, block 256 (wave = r, lane = row/col)
__global__ __launch_bounds__(256) void k_linkfb(const float* __restrict__ link_prev,
    const float* __restrict__ rw_prev, const float* __restrict__ e_ws,
    const float* __restrict__ prec_prev, const float* __restrict__ ww_ws,
    float* __restrict__ fwd_part, float* __restrict__ bwd_part){
  __shared__ float Lt[64][68];   // pad 68: 16B-aligned rows, conflict-free col reads
  int band = blockIdx.x, ct = blockIdx.y, b = blockIdx.z, t = threadIdx.x;
  int r = t >> 6, lane = t & 63;
  int ru = __builtin_amdgcn_readfirstlane(r);  // wave-uniform -> scalar loads below
  const float4* L4 = (const float4*)link_prev;
  #pragma unroll
  for (int q = 0; q < 4; ++q){
    int idx = t + 256*q;
    int row = idx >> 4, c4 = idx & 15;
    float4 v = L4[((long)b << 18) + (long)(band*64+row)*256 + ct*16 + c4];
    *(float4*)&Lt[row][c4*4] = v;
  }
  const float* aJ = rw_prev + (long)(b*4+ru)*1024 + ct*64;
  const float* eJ = e_ws    + (long)(b*4+ru)*1024 + ct*64;
  const float* aI = rw_prev + (long)(b*4+ru)*1024 + band*64;
  const float* eI = e_ws    + (long)(b*4+ru)*1024 + band*64;
  // tile-local scalars: Pt = sum_j p_j a[r,j]; Wt = sum_i e[r,i]
  float pv = prec_prev[b*1024 + ct*64 + lane] * aJ[lane];
  float wvs = eI[lane];
  for (int o = 32; o > 0; o >>= 1){ pv += __shfl_xor(pv,o); wvs += __shfl_xor(wvs,o); }
  float wwi = ww_ws[b*1024 + band*64 + lane];
  float wwc = ww_ws[b*1024 + ct*64 + lane];
  float pc  = prec_prev[b*1024 + ct*64 + lane];
  __syncthreads();
  // fwd: thread (r, row=lane)
  float A1 = 0.0f, A2 = 0.0f;
  for (int jc = 0; jc < 64; jc += 4){
    float4 Lv = *(const float4*)&Lt[lane][jc];
    A1 += Lv.x*aJ[jc] + Lv.y*aJ[jc+1] + Lv.z*aJ[jc+2] + Lv.w*aJ[jc+3];
    A2 += Lv.x*eJ[jc] + Lv.y*eJ[jc+1] + Lv.z*eJ[jc+2] + Lv.w*eJ[jc+3];
  }
  float facc = (1.0f - wwi)*A1 - A2 + wwi*pv;
  // bwd: thread (r, col=lane)
  float B1 = 0.0f, B2 = 0.0f;
  for (int rowl = 0; rowl < 64; ++rowl){
    float Lv = Lt[rowl][lane];
    B1 += Lv * aI[rowl];
    B2 += Lv * eI[rowl];
  }
  float bacc = (1.0f - wwc)*B1 - B2 + pc*wvs;
  if (band == ct){  // diagonal correction: formula included ((1-2ww)L + ww*p)*a at i==j
    float D = ((1.0f - 2.0f*wwi)*Lt[lane][lane] + wwi*pc)*aJ[lane];
    facc -= D;
    bacc -= D;
  }
  fwd_part[(long)ct*65536 + (long)(b*4+r)*1024 + band*64 + lane] = facc;
  bwd_part[(long)band*65536 + (long)(b*4+r)*1024 + ct*64 + lane] = bacc;
}

// ---------------- K7b: reduce partials — grid 64, block 1024 ----------------
__global__ void k_fbred(const float* __restrict__ fwd_part, const float* __restrict__ bwd_part,
                        float* __restrict__ fwd_ws, float* __restrict__ bwd_ws){
  int idx = blockIdx.x*1024 + threadIdx.x;
  float f = 0.0f, bsum = 0.0f;
  #pragma unroll
  for (int c = 0; c < 16; ++c){
    f    += fwd_part[(long)c*65536 + idx];
    bsum += bwd_part[(long)c*65536 + idx];
  }
  fwd_ws[idx] = f;
  bwd_ws[idx] = bsum;
}

// ---------------- K8: read softmax + mix + rv (mem recomputed) — grid (4,16), block 1024 ----------------
__global__ void k_read(const float* __restrict__ rdot_ws, const float* __restrict__ mnorm_ws,
                       const float* __restrict__ ifa_ws, const float* __restrict__ fwd_ws,
                       const float* __restrict__ bwd_ws, const float* __restrict__ mem_prev,
                       const float* __restrict__ ww_ws, float* __restrict__ rv_ws){
  __shared__ float red[1024]; __shared__ float wrs[1024]; __shared__ float wwsh[1024];
  __shared__ float par[1];
  int r = blockIdx.x, b = blockIdx.y, t = threadIdx.x; // a = t
  const float* ifa = ifa_ws + b*512;
  if (t == 0){
    float s = 0;
    for (int m = 0; m < 64; ++m){ float v = ifa[r*64+m]; s += v*v; }
    par[0] = sqrtf(s);
  }
  wwsh[t] = ww_ws[b*1024+t];
  __syncthreads();
  float kn = par[0], beta = ifa[256 + r];
  float sc = beta * rdot_ws[(long)(b*4+r)*1024 + t] / (kn*mnorm_ws[b*1024+t] + 1e-6f);
  red[t] = sc; __syncthreads();
  for (int s = 512; s > 0; s >>= 1){ if (t < s) red[t] = fmaxf(red[t], red[t+s]); __syncthreads(); }
  float mx = red[0]; __syncthreads();
  float e = expf(sc - mx);
  red[t] = e; __syncthreads();
  for (int s = 512; s > 0; s >>= 1){ if (t < s) red[t] += red[t+s]; __syncthreads(); }
  float cr = e / red[0];
  __syncthreads();
  float p0 = ifa[459+3*r], p1 = ifa[460+3*r], p2 = ifa[461+3*r];
  wrs[t] = p0*bwd_ws[(long)(b*4+r)*1024 + t] + p1*cr + p2*fwd_ws[(long)(b*4+r)*1024 + t];
  __syncthreads();
  int m = t & 63, ch = t >> 6;
  float er = ifa[325+m], wv = ifa[389+m];
  float acc = 0;
  for (int q = 0; q < 64; ++q){
    int a = ch*64 + q;
    float w = wwsh[a];
    float v = mem_prev[((long)b*1024 + a)*64 + m]*(1.0f - w*er) + w*wv;
    acc += wrs[a]*v;
  }
  red[ch*64 + m] = acc;
  __syncthreads();
  if (t < 64){
    float s = 0;
    for (int c2 = 0; c2 < 16; ++c2) s += red[c2*64 + t];
    rv_ws[(b*4+r)*64 + t] = s;
  }
}

// ---------------- K9: out = out_hidden + rv@W_rd + b_rd — grid 16, block 1024 (4-way K split) ----------------
__global__ void k_out(const float* __restrict__ outh_ws, const float* __restrict__ rv_ws,
                      const float* __restrict__ W_rd, const float* __restrict__ b_rd,
                      float* __restrict__ out){
  __shared__ float rvs[256]; __shared__ float part[4][256];
  int b = blockIdx.x, t = threadIdx.x;
  int o = t & 255, kq = t >> 8;
  if (t < 256) rvs[t] = rv_ws[b*256 + t];
  __syncthreads();
  float acc = 0.0f;
  for (int q = kq*64; q < kq*64 + 64; ++q) acc += rvs[q]*W_rd[(long)q*256 + o];
  part[kq][o] = acc;
  __syncthreads();
  if (t < 256)
    out[b*256+t] = outh_ws[b*256+t] + b_rd[t] + part[0][t] + part[1][t] + part[2][t] + part[3][t];
}

extern "C" void kernel_launch(void* const* d_in, const int* in_sizes, int n_in,
                              void* d_out, int out_size, void* d_ws, size_t ws_size,
                              hipStream_t stream){
  const float* x          = (const float*)d_in[0];
  const float* h_prev     = (const float*)d_in[1];
  const float* c_prev     = (const float*)d_in[2];
  const float* mem_prev   = (const float*)d_in[3];
  const float* rw_prev    = (const float*)d_in[4];
  const float* ww_prev    = (const float*)d_in[5];
  const float* usage_prev = (const float*)d_in[6];
  const float* prec_prev  = (const float*)d_in[7];
  const float* link_prev  = (const float*)d_in[8];
  const float* rv_prev    = (const float*)d_in[9];
  const float* Wx         = (const float*)d_in[10];
  const float* Wh         = (const float*)d_in[11];
  const float* b_lstm     = (const float*)d_in[12];
  const float* W_hid      = (const float*)d_in[13];
  const float* b_hid      = (const float*)d_in[14];
  const float* W_if       = (const float*)d_in[15];
  const float* b_if       = (const float*)d_in[16];
  const float* W_rd       = (const float*)d_in[17];
  const float* b_rd       = (const float*)d_in[18];
  float* out = (float*)d_out;

  // ws layout (floats), total 3178496 = 12.7 MB
  float* ws = (float*)d_ws;
  float* h_ws     = ws + 0;          // 8192
  float* ifr_ws   = ws + 8192;       // 8192
  float* ifa_ws   = ws + 16384;      // 8192
  float* outh_ws  = ws + 24576;      // 4096
  float* alloc_ws = ws + 28672;      // 16384
  float* ww_ws    = ws + 45056;      // 16384
  float* mnorm_ws = ws + 61440;      // 16384
  float* wsc_ws   = ws + 77824;      // 16384
  float* rv_ws    = ws + 94208;      // 4096
  float* fwd_ws   = ws + 98304;      // 65536
  float* bwd_ws   = ws + 163840;     // 65536
  float* rdot_ws  = ws + 229376;     // 65536
  float* e_ws     = ws + 294912;     // 65536
  float* zpart    = ws + 360448;     // 524288
  float* ifpart   = ws + 884736;     // 196608
  float* fwd_part = ws + 1081344;    // 1048576 (16 ct x 65536)
  float* bwd_part = ws + 2129920;    // 1048576 (16 band x 65536)

  k_lstm_part<<<dim3(8,16,2),256,0,stream>>>(x, rv_prev, h_prev, Wx, Wh, zpart);
  k_lstm_fin<<<dim3(4,16),128,0,stream>>>(zpart, b_lstm, c_prev, h_ws);
  k_iface_part<<<dim3(3,16,2),256,0,stream>>>(h_ws, W_if, W_hid, ifpart);
  k_iface_fin<<<16,768,0,stream>>>(ifpart, b_if, b_hid, ifr_ws, outh_ws);
  k_act_alloc<<<16,1024,0,stream>>>(ifr_ws, rw_prev, ww_prev, usage_prev, ifa_ws, alloc_ws);
  k_wscore<<<dim3(16,16),256,0,stream>>>(mem_prev, ifa_ws, wsc_ws);
  k_cw_ww<<<16,1024,0,stream>>>(wsc_ws, ifa_ws, alloc_ws, rw_prev, ww_ws, e_ws);
  k_score<<<dim3(16,16),256,0,stream>>>(mem_prev, ww_ws, ifa_ws, mnorm_ws, rdot_ws);
  k_linkfb<<<dim3(16,16,16),256,0,stream>>>(link_prev, rw_prev, e_ws, prec_prev, ww_ws,
                                            fwd_part, bwd_part);
  k_fbred<<<64,1024,0,stream>>>(fwd_part, bwd_part, fwd_ws, bwd_ws);
  k_read<<<dim3(4,16),1024,0,stream>>>(rdot_ws, mnorm_ws, ifa_ws, fwd_ws, bwd_ws,
                                       mem_prev, ww_ws, rv_ws);
  k_out<<<16,1024,0,stream>>>(outh_ws, rv_ws, W_rd, b_rd, out);
}